// Round 1
// baseline (711.317 us; speedup 1.0000x reference)
//
#include <hip/hip_runtime.h>
#include <math.h>

constexpr int NNODES  = 102400;
constexpr int NEDGES  = 409600;
constexpr int NGRAPHS = 2048;
constexpr int HIDDEN  = 128;

typedef __attribute__((ext_vector_type(8))) short s16x8;
typedef __attribute__((ext_vector_type(4))) float f32x4;

__device__ __forceinline__ float relu_f(float v) { return fmaxf(v, 0.0f); }

// exact 3-way bf16 truncation split: x == b0 + b1 + b2
__device__ __forceinline__ void split3(float x, short& s0, short& s1, short& s2) {
  unsigned u0 = __float_as_uint(x);
  s0 = (short)(u0 >> 16);
  float r1 = x - __uint_as_float(u0 & 0xFFFF0000u);
  unsigned u1 = __float_as_uint(r1);
  s1 = (short)(u1 >> 16);
  float r2 = r1 - __uint_as_float(u1 & 0xFFFF0000u);
  s2 = (short)(__float_as_uint(r2) >> 16);
}

// ---------------- prep: histograms + weight-split (merged) ----------------
__global__ void prep_kernel(const int* __restrict__ ei, const int* __restrict__ batch,
                            int* __restrict__ counts, int* __restrict__ gcounts,
                            const float* __restrict__ W10, const float* __restrict__ W20,
                            const float* __restrict__ W11, const float* __restrict__ W21,
                            const float* __restrict__ W12, const float* __restrict__ W22,
                            short* __restrict__ ws) {
  int b = blockIdx.x;
  if (b < NEDGES / 256) {
    atomicAdd(&counts[ei[NEDGES + b * 256 + threadIdx.x]], 1);
    return;
  }
  if (b < NEDGES / 256 + NNODES / 256) {
    atomicAdd(&gcounts[batch[(b - NEDGES / 256) * 256 + threadIdx.x]], 1);
    return;
  }
  int bw = b - (NEDGES / 256 + NNODES / 256);
  int n = threadIdx.x;
  if (n >= 128) return;
  const float* src; long base; int k, realK, KP;
  if (bw < 96) {
    src = W10; base = 0; k = bw; realK = 78; KP = 96;
  } else {
    int q = bw - 96;
    int mat = q >> 7;
    k = q & 127; realK = 128; KP = 128;
    const float* srcs[5] = {W20, W11, W21, W12, W22};
    const long bases[5] = {36864, 86016, 135168, 184320, 233472};
    src = srcs[mat]; base = bases[mat];
  }
  float x = (k < realK) ? src[k * 128 + n] : 0.0f;
  short s0, s1, s2;
  split3(x, s0, s1, s2);
  long e = base + ((long)(k >> 5) * 128 + n) * 32 + (k & 31);
  long ps = (long)KP * 128;
  ws[e] = s0; ws[e + ps] = s1; ws[e + 2 * ps] = s2;
}

// ---------------- merged scans ----------------
__device__ __forceinline__ void scan_block_body(const int* in, int n, int* out_excl,
                                                int* bsums, int lb) {
  __shared__ int s[256];
  int t = threadIdx.x;
  int i = lb * 256 + t;
  int v = (i < n) ? in[i] : 0;
  s[t] = v;
  __syncthreads();
  for (int off = 1; off < 256; off <<= 1) {
    int x = (t >= off) ? s[t - off] : 0;
    __syncthreads();
    s[t] += x;
    __syncthreads();
  }
  if (i < n) out_excl[i] = s[t] - v;
  if (t == 255) bsums[lb] = s[255];
}

__global__ void scan_block2_kernel(const int* __restrict__ counts, int* __restrict__ row_ptr,
                                   int* __restrict__ bsumsA, const int* __restrict__ gcounts,
                                   int* __restrict__ gptr, int* __restrict__ bsumsB) {
  int b = blockIdx.x;
  if (b < NNODES / 256) scan_block_body(counts, NNODES, row_ptr, bsumsA, b);
  else scan_block_body(gcounts, NGRAPHS, gptr, bsumsB, b - NNODES / 256);
}

__global__ void scan_top2_kernel(int* __restrict__ bsumsA, int* __restrict__ bsumsB) {
  __shared__ int s[1024];
  int* bs = (blockIdx.x == 0) ? bsumsA : bsumsB;
  int nb  = (blockIdx.x == 0) ? (NNODES / 256) : (NGRAPHS / 256);
  int t = threadIdx.x;
  int v = (t < nb) ? bs[t] : 0;
  s[t] = v;
  __syncthreads();
  for (int off = 1; off < 1024; off <<= 1) {
    int x = (t >= off) ? s[t - off] : 0;
    __syncthreads();
    s[t] += x;
    __syncthreads();
  }
  if (t < nb) bs[t] = s[t] - v;
  if (t == 1023) bs[nb] = s[1023];
}

__global__ void scan_add2_kernel(int* __restrict__ row_ptr, const int* __restrict__ bsumsA,
                                 int* __restrict__ nxt, int* __restrict__ gptr,
                                 const int* __restrict__ bsumsB) {
  int b = blockIdx.x, t = threadIdx.x;
  if (b < NNODES / 256) {
    int i = b * 256 + t;
    int v = row_ptr[i] + bsumsA[b];
    row_ptr[i] = v;
    nxt[i] = v;
    if (i == 0) row_ptr[NNODES] = bsumsA[NNODES / 256];
  } else {
    int lb = b - NNODES / 256;
    int i = lb * 256 + t;
    gptr[i] += bsumsB[lb];
    if (i == 0) gptr[NGRAPHS] = bsumsB[NGRAPHS / 256];
  }
}

__global__ void scatter_kernel(const int* __restrict__ ei, int* __restrict__ nxt,
                               int* __restrict__ csr_sd) {
  int e = blockIdx.x * blockDim.x + threadIdx.x;
  if (e < NEDGES) {
    int s = ei[e];
    int d = ei[NEDGES + e];
    int pos = atomicAdd(&nxt[d], 1);
    *(int2*)&csr_sd[2 * pos] = make_int2(s, d);
  }
}

// ---------------- GIN block body ----------------
// Gather: FLAT SEGMENTED EDGE STREAM. Edges of the block's 32 nodes are
// contiguous in CSR [row_ptr[base], row_ptr[base+32]); split evenly over
// half-waves (f4) / waves (f2). Per edge: one packed int2 (src,dst) read
// (sequential, prefetched 2*D ahead) + one independent row load (depth-D
// rolling pipeline). Register segment-accumulate, flush to LDS via
// ds_add_f32 at dst boundaries. Self term pre-initializes the LDS tile.
// Then MFMA mm1/mm2 via exact bf16x3 split.
constexpr int STRK = 132;
template<int DIN, int KP1, bool XF, bool G4>
__device__ __forceinline__ void gin_block(
    int bid, const float* __restrict__ X,
    const int* __restrict__ row_ptr, const int* __restrict__ csr_sd,
    const short* __restrict__ w1s, const float* __restrict__ b1,
    const short* __restrict__ w2s, const float* __restrict__ b2,
    const float* __restrict__ psum, const float* __restrict__ psq,
    const float* __restrict__ bg, const float* __restrict__ bb2,
    float* __restrict__ O, float* __restrict__ bn_sum, float* __restrict__ bn_sq,
    float* buf) {
  const int t = threadIdx.x;
  const int wv = t >> 6, lane = t & 63;
  const int base = bid * 32;
  __shared__ float scs[128], shs[128];

  const int E0 = row_ptr[base];
  const int L  = row_ptr[base + 32] - E0;

  if (G4) {
    // ---- stage BN-relu coefs of previous layer in LDS
    if (XF) {
      if (t < 128) {
        const float mu = psum[t] * (1.0f / NNODES);
        const float va = fmaxf(psq[t] * (1.0f / NNODES) - mu * mu, 0.0f);
        const float s = bg[t] / sqrtf(va + 1e-5f);
        scs[t] = s;
        shs[t] = bb2[t] - mu * s;
      }
      __syncthreads();
    }
    // ---- self-term init of LDS tile (coalesced)
    for (int i = t; i < 1024; i += 256) {
      const int m = i >> 5, c = (i & 31) << 2;
      float4 s = *(const float4*)&X[(long)(base + m) * DIN + c];
      if (XF) {
        s.x = relu_f(fmaf(s.x, scs[c],     shs[c]));
        s.y = relu_f(fmaf(s.y, scs[c + 1], shs[c + 1]));
        s.z = relu_f(fmaf(s.z, scs[c + 2], shs[c + 2]));
        s.w = relu_f(fmaf(s.w, scs[c + 3], shs[c + 3]));
      }
      *(float4*)&buf[m * STRK + c] = s;
    }
    const int h = t >> 5;           // half-wave 0..7
    const int f = (t & 31) << 2;    // feature quad
    float sc0 = 1.f, sc1 = 1.f, sc2 = 1.f, sc3 = 1.f;
    float sh0 = 0.f, sh1 = 0.f, sh2 = 0.f, sh3 = 0.f;
    if (XF) {
      sc0 = scs[f]; sc1 = scs[f + 1]; sc2 = scs[f + 2]; sc3 = scs[f + 3];
      sh0 = shs[f]; sh1 = shs[f + 1]; sh2 = shs[f + 2]; sh3 = shs[f + 3];
    }
    const int js = E0 + ((h * L) >> 3);
    const int je = E0 + (((h + 1) * L) >> 3);
    __syncthreads();

    constexpr int D = 4;
    int2 csd[D], nsd[D];
    float4 u[D];
#pragma unroll
    for (int p = 0; p < D; ++p)
      csd[p] = *(const int2*)&csr_sd[2 * min(js + p, NEDGES - 1)];
#pragma unroll
    for (int p = 0; p < D; ++p)
      u[p] = *(const float4*)&X[(long)csd[p].x * DIN + f];
#pragma unroll
    for (int p = 0; p < D; ++p)
      nsd[p] = *(const int2*)&csr_sd[2 * min(js + D + p, NEDGES - 1)];

    float4 acc = make_float4(0.f, 0.f, 0.f, 0.f);
    int cur = -1;
    auto consume = [&](int p) {
      const int d = csd[p].y - base;
      if (d != cur) {
        if (cur >= 0) {
          float* pb = &buf[cur * STRK + f];
          atomicAdd(pb + 0, acc.x); atomicAdd(pb + 1, acc.y);
          atomicAdd(pb + 2, acc.z); atomicAdd(pb + 3, acc.w);
        }
        cur = d;
        acc = make_float4(0.f, 0.f, 0.f, 0.f);
      }
      const float4 v = u[p];
      if (XF) {
        acc.x += relu_f(fmaf(v.x, sc0, sh0));
        acc.y += relu_f(fmaf(v.y, sc1, sh1));
        acc.z += relu_f(fmaf(v.z, sc2, sh2));
        acc.w += relu_f(fmaf(v.w, sc3, sh3));
      } else {
        acc.x += v.x; acc.y += v.y; acc.z += v.z; acc.w += v.w;
      }
    };
    int j = js;
    for (; j + D <= je; j += D) {
#pragma unroll
      for (int p = 0; p < D; ++p) {
        consume(p);
        csd[p] = nsd[p];
        u[p] = *(const float4*)&X[(long)csd[p].x * DIN + f];
        nsd[p] = *(const int2*)&csr_sd[2 * min(j + 2 * D + p, NEDGES - 1)];
      }
    }
#pragma unroll
    for (int p = 0; p < D; ++p)
      if (j + p < je) consume(p);
    if (cur >= 0) {
      float* pb = &buf[cur * STRK + f];
      atomicAdd(pb + 0, acc.x); atomicAdd(pb + 1, acc.y);
      atomicAdd(pb + 2, acc.z); atomicAdd(pb + 3, acc.w);
    }
  } else {
    // ---- layer 0: float2 lanes (78 = 39 pairs), full-wave edge unit
    for (int i = t; i < 1536; i += 256) {
      const int m = i / 48, c = (i % 48) << 1;
      float2 v = make_float2(0.f, 0.f);
      if (c < DIN) v = *(const float2*)&X[(long)(base + m) * DIN + c];
      *(float2*)&buf[m * STRK + c] = v;
    }
    const int c2 = lane << 1;
    const bool ld = (c2 < DIN);
    const int cL = ld ? c2 : 0;
    const int js = E0 + ((wv * L) >> 2);
    const int je = E0 + (((wv + 1) * L) >> 2);
    __syncthreads();

    constexpr int D2 = 8;
    int2 csd[D2], nsd[D2];
    float2 u[D2];
#pragma unroll
    for (int p = 0; p < D2; ++p)
      csd[p] = *(const int2*)&csr_sd[2 * min(js + p, NEDGES - 1)];
#pragma unroll
    for (int p = 0; p < D2; ++p)
      u[p] = *(const float2*)&X[(long)csd[p].x * DIN + cL];
#pragma unroll
    for (int p = 0; p < D2; ++p)
      nsd[p] = *(const int2*)&csr_sd[2 * min(js + D2 + p, NEDGES - 1)];

    float ax = 0.f, ay = 0.f;
    int cur = -1;
    auto consume2 = [&](int p) {
      const int d = csd[p].y - base;
      if (d != cur) {
        if (cur >= 0 && ld) {
          float* pb = &buf[cur * STRK + c2];
          atomicAdd(pb + 0, ax); atomicAdd(pb + 1, ay);
        }
        cur = d; ax = 0.f; ay = 0.f;
      }
      ax += u[p].x; ay += u[p].y;
    };
    int j = js;
    for (; j + D2 <= je; j += D2) {
#pragma unroll
      for (int p = 0; p < D2; ++p) {
        consume2(p);
        csd[p] = nsd[p];
        u[p] = *(const float2*)&X[(long)csd[p].x * DIN + cL];
        nsd[p] = *(const int2*)&csr_sd[2 * min(j + 2 * D2 + p, NEDGES - 1)];
      }
    }
#pragma unroll
    for (int p = 0; p < D2; ++p)
      if (j + p < je) consume2(p);
    if (cur >= 0 && ld) {
      float* pb = &buf[cur * STRK + c2];
      atomicAdd(pb + 0, ax); atomicAdd(pb + 1, ay);
    }
  }
  __syncthreads();

  const int rb = wv & 1, nbase = (wv >> 1) * 64;
  const int l15 = lane & 15, quad = lane >> 4;
  const int aoff = (rb * 16 + l15) * STRK;
  constexpr int PS1 = KP1 * 128;
  constexpr int PS2 = 128 * 128;

  // ---- mm1 (MFMA): acc1 = h @ W1
  f32x4 acc1[4] = {};
  for (int ks = 0; ks < KP1 / 32; ++ks) {
    const int k0 = ks * 32;
    const float4 xa = *(const float4*)&buf[aoff + k0 + quad * 8];
    const float4 xb = *(const float4*)&buf[aoff + k0 + quad * 8 + 4];
    s16x8 A0, A1, A2;
    {
      const float xv[8] = {xa.x, xa.y, xa.z, xa.w, xb.x, xb.y, xb.z, xb.w};
#pragma unroll
      for (int j = 0; j < 8; ++j) {
        short s0, s1, s2;
        split3(xv[j], s0, s1, s2);
        A0[j] = s0; A1[j] = s1; A2[j] = s2;
      }
    }
    s16x8 B0[4], B1[4], B2[4];
#pragma unroll
    for (int ct = 0; ct < 4; ++ct) {
      const int n = nbase + ct * 16 + l15;
      const short* wp = w1s + ((long)(ks * 128 + n) << 5) + (quad << 3);
      B0[ct] = *(const s16x8*)(wp);
      B1[ct] = *(const s16x8*)(wp + PS1);
      B2[ct] = *(const s16x8*)(wp + 2 * PS1);
    }
#pragma unroll
    for (int ct = 0; ct < 4; ++ct) acc1[ct] = __builtin_amdgcn_mfma_f32_16x16x32_bf16(A0, B2[ct], acc1[ct], 0, 0, 0);
#pragma unroll
    for (int ct = 0; ct < 4; ++ct) acc1[ct] = __builtin_amdgcn_mfma_f32_16x16x32_bf16(A1, B1[ct], acc1[ct], 0, 0, 0);
#pragma unroll
    for (int ct = 0; ct < 4; ++ct) acc1[ct] = __builtin_amdgcn_mfma_f32_16x16x32_bf16(A2, B0[ct], acc1[ct], 0, 0, 0);
#pragma unroll
    for (int ct = 0; ct < 4; ++ct) acc1[ct] = __builtin_amdgcn_mfma_f32_16x16x32_bf16(A0, B1[ct], acc1[ct], 0, 0, 0);
#pragma unroll
    for (int ct = 0; ct < 4; ++ct) acc1[ct] = __builtin_amdgcn_mfma_f32_16x16x32_bf16(A1, B0[ct], acc1[ct], 0, 0, 0);
#pragma unroll
    for (int ct = 0; ct < 4; ++ct) acc1[ct] = __builtin_amdgcn_mfma_f32_16x16x32_bf16(A0, B0[ct], acc1[ct], 0, 0, 0);
  }
  __syncthreads();

  // mid = relu(acc1 + b1), stored [m][j]
#pragma unroll
  for (int ct = 0; ct < 4; ++ct) {
    const int n = nbase + ct * 16 + l15;
    const float bb = b1[n];
#pragma unroll
    for (int reg = 0; reg < 4; ++reg) {
      const int m = rb * 16 + quad * 4 + reg;
      buf[m * STRK + n] = relu_f(acc1[ct][reg] + bb);
    }
  }
  __syncthreads();

  // ---- mm2 (MFMA)
  f32x4 acc2[4] = {};
  for (int ks = 0; ks < 4; ++ks) {
    const int k0 = ks * 32;
    const float4 xa = *(const float4*)&buf[aoff + k0 + quad * 8];
    const float4 xb = *(const float4*)&buf[aoff + k0 + quad * 8 + 4];
    s16x8 A0, A1, A2;
    {
      const float xv[8] = {xa.x, xa.y, xa.z, xa.w, xb.x, xb.y, xb.z, xb.w};
#pragma unroll
      for (int j = 0; j < 8; ++j) {
        short s0, s1, s2;
        split3(xv[j], s0, s1, s2);
        A0[j] = s0; A1[j] = s1; A2[j] = s2;
      }
    }
    s16x8 B0[4], B1[4], B2[4];
#pragma unroll
    for (int ct = 0; ct < 4; ++ct) {
      const int n = nbase + ct * 16 + l15;
      const short* wp = w2s + ((long)(ks * 128 + n) << 5) + (quad << 3);
      B0[ct] = *(const s16x8*)(wp);
      B1[ct] = *(const s16x8*)(wp + PS2);
      B2[ct] = *(const s16x8*)(wp + 2 * PS2);
    }
#pragma unroll
    for (int ct = 0; ct < 4; ++ct) acc2[ct] = __builtin_amdgcn_mfma_f32_16x16x32_bf16(A0, B2[ct], acc2[ct], 0, 0, 0);
#pragma unroll
    for (int ct = 0; ct < 4; ++ct) acc2[ct] = __builtin_amdgcn_mfma_f32_16x16x32_bf16(A1, B1[ct], acc2[ct], 0, 0, 0);
#pragma unroll
    for (int ct = 0; ct < 4; ++ct) acc2[ct] = __builtin_amdgcn_mfma_f32_16x16x32_bf16(A2, B0[ct], acc2[ct], 0, 0, 0);
#pragma unroll
    for (int ct = 0; ct < 4; ++ct) acc2[ct] = __builtin_amdgcn_mfma_f32_16x16x32_bf16(A0, B1[ct], acc2[ct], 0, 0, 0);
#pragma unroll
    for (int ct = 0; ct < 4; ++ct) acc2[ct] = __builtin_amdgcn_mfma_f32_16x16x32_bf16(A1, B0[ct], acc2[ct], 0, 0, 0);
#pragma unroll
    for (int ct = 0; ct < 4; ++ct) acc2[ct] = __builtin_amdgcn_mfma_f32_16x16x32_bf16(A0, B0[ct], acc2[ct], 0, 0, 0);
  }

  // epilogue
  float cs[4], cq[4];
#pragma unroll
  for (int ct = 0; ct < 4; ++ct) {
    const int n = nbase + ct * 16 + l15;
    const float bb = b2[n];
    float s = 0.f, q = 0.f;
#pragma unroll
    for (int reg = 0; reg < 4; ++reg) {
      const int m = rb * 16 + quad * 4 + reg;
      const float o = acc2[ct][reg] + bb;
      O[(long)(base + m) * HIDDEN + n] = o;
      s += o;
      q = fmaf(o, o, q);
    }
    cs[ct] = s; cq[ct] = q;
  }
  __syncthreads();
  const int g = rb * 4 + quad;
#pragma unroll
  for (int ct = 0; ct < 4; ++ct) {
    const int n = nbase + ct * 16 + l15;
    buf[n * 8 + g] = cs[ct];
    buf[1024 + n * 8 + g] = cq[ct];
  }
  __syncthreads();
  if (t < HIDDEN) {
    float s = 0.f, q = 0.f;
    for (int gg = 0; gg < 8; ++gg) { s += buf[t * 8 + gg]; q += buf[1024 + t * 8 + gg]; }
    atomicAdd(&bn_sum[t], s);
    atomicAdd(&bn_sq[t], q);
  }
}

// ---------------- a2h split-K block ----------------
constexpr int A2H_K = 3000, A2H_SPLIT = 200, A2H_NSPLIT = 15;
__device__ __forceinline__ void a2h_block(int rb, int sp, const float* __restrict__ A,
    const float* __restrict__ W, const float* __restrict__ bias, float* __restrict__ XA,
    float* xT) {
  constexpr int STR = 18;
  const int t = threadIdx.x;
  const int row0 = rb * 16;
  const int k0 = sp * A2H_SPLIT;
  for (int i = t; i < 16 * 50; i += 256) {
    const int r = i / 50, kq = i - r * 50;
    const float4 v = *(const float4*)&A[(long)(row0 + r) * A2H_K + k0 + kq * 4];
    xT[(kq * 4 + 0) * STR + r] = v.x;
    xT[(kq * 4 + 1) * STR + r] = v.y;
    xT[(kq * 4 + 2) * STR + r] = v.z;
    xT[(kq * 4 + 3) * STR + r] = v.w;
  }
  __syncthreads();
  const int rg = t >> 5, cg = t & 31;
  const int r0 = rg * 2, j0 = cg * 4;
  float acc[2][4];
  for (int r = 0; r < 2; ++r)
    for (int c = 0; c < 4; ++c) acc[r][c] = 0.f;
  const float* Wp = W + (long)k0 * HIDDEN + j0;
  for (int k = 0; k < A2H_SPLIT; ++k) {
    const float4 w = *(const float4*)&Wp[(long)k * HIDDEN];
    const float2 x = *(const float2*)&xT[k * STR + r0];
    const float wa[4] = {w.x, w.y, w.z, w.w};
    for (int c = 0; c < 4; ++c) {
      acc[0][c] = fmaf(x.x, wa[c], acc[0][c]);
      acc[1][c] = fmaf(x.y, wa[c], acc[1][c]);
    }
  }
  if (sp == 0)
    for (int c = 0; c < 4; ++c) { acc[0][c] += bias[j0 + c]; acc[1][c] += bias[j0 + c]; }
  for (int r = 0; r < 2; ++r)
    for (int c = 0; c < 4; ++c)
      atomicAdd(&XA[(long)(row0 + r0 + r) * HIDDEN + j0 + c], acc[r][c]);
}

// ---------------- conv block ----------------
__device__ __forceinline__ void conv_block(int g, const float* __restrict__ PS,
    const float* __restrict__ CK, const float* __restrict__ CB, float* __restrict__ XP,
    float* seq) {
  const int t = threadIdx.x;
  for (int i = t; i < 1000; i += 256) seq[i] = PS[g * 1000 + i];
  __syncthreads();
  const int pl = t & 31, cgp = t >> 5;
  float kr[4][8];
  for (int cc = 0; cc < 4; ++cc)
    for (int k = 0; k < 8; ++k) kr[cc][k] = CK[(cgp * 4 + cc) * 8 + k];
  float m[4] = {-1e30f, -1e30f, -1e30f, -1e30f};
  for (int i = 0; i < 32; ++i) {
    int p = pl + 32 * i;
    if (p < 993) {
      float sv[8];
      for (int k = 0; k < 8; ++k) sv[k] = seq[p + k];
      for (int cc = 0; cc < 4; ++cc) {
        float s = 0.f;
        for (int k = 0; k < 8; ++k) s = fmaf(sv[k], kr[cc][k], s);
        m[cc] = fmaxf(m[cc], s);
      }
    }
  }
  for (int off = 16; off >= 1; off >>= 1)
    for (int cc = 0; cc < 4; ++cc) m[cc] = fmaxf(m[cc], __shfl_xor(m[cc], off));
  if (pl == 0)
    for (int cc = 0; cc < 4; ++cc)
      XP[g * 32 + cgp * 4 + cc] = relu_f(m[cc] + CB[cgp * 4 + cc]);
}

// ---------------- fat0: gin0 + a2h + conv ----------------
__global__ __launch_bounds__(256, 4) void fat0_kernel(
    const float* __restrict__ x_lig, const int* __restrict__ row_ptr,
    const int* __restrict__ csr_sd,
    const short* __restrict__ ws, const float* __restrict__ b1,
    const float* __restrict__ b2,
    float* __restrict__ O0, float* __restrict__ bn_sum, float* __restrict__ bn_sq,
    const float* __restrict__ a2h, const float* __restrict__ a1W,
    const float* __restrict__ a1b, float* __restrict__ XA,
    const float* __restrict__ pseq, const float* __restrict__ convk,
    const float* __restrict__ convb, float* __restrict__ XP32) {
  __shared__ __align__(16) float buf[32 * STRK];
  const int b = blockIdx.x;
  if (b < NNODES / 32) {
    gin_block<78, 96, false, false>(b, x_lig, row_ptr, csr_sd, ws, b1, ws + 36864, b2,
                                    nullptr, nullptr, nullptr, nullptr, O0, bn_sum, bn_sq, buf);
  } else if (b < NNODES / 32 + (NGRAPHS / 16) * A2H_NSPLIT) {
    const int q = b - NNODES / 32;
    a2h_block(q & 127, q >> 7, a2h, a1W, a1b, XA, buf);
  } else {
    conv_block(b - (NNODES / 32 + (NGRAPHS / 16) * A2H_NSPLIT), pseq, convk, convb, XP32, buf);
  }
}

// ---------------- gin wrapper (layers 1,2; flat-stream gather, inline BN) ----------------
__global__ __launch_bounds__(256, 4) void gin_kernel(
    const float* __restrict__ X, const int* __restrict__ row_ptr,
    const int* __restrict__ csr_sd,
    const short* __restrict__ w1s, const float* __restrict__ b1,
    const short* __restrict__ w2s, const float* __restrict__ b2,
    const float* __restrict__ psum, const float* __restrict__ psq,
    const float* __restrict__ bg, const float* __restrict__ bb2,
    float* __restrict__ O, float* __restrict__ bn_sum, float* __restrict__ bn_sq) {
  __shared__ __align__(16) float buf[32 * STRK];
  gin_block<128, 128, true, true>(blockIdx.x, X, row_ptr, csr_sd, w1s, b1, w2s, b2,
                                  psum, psq, bg, bb2, O, bn_sum, bn_sq, buf);
}

// ---------------- mega-head: pool(BN2 inline) + 3 branch gemms + c1 + c2 + out ----------------
__global__ __launch_bounds__(256) void head_kernel(
    const float* __restrict__ O, const int* __restrict__ gp,
    const float* __restrict__ psum, const float* __restrict__ psq,
    const float* __restrict__ bg, const float* __restrict__ bb2,
    const float* __restrict__ XP32, const float* __restrict__ XA,
    const float* __restrict__ ligW, const float* __restrict__ ligb,
    const float* __restrict__ protW, const float* __restrict__ protb,
    const float* __restrict__ a2W, const float* __restrict__ a2b,
    const float* __restrict__ c1W, const float* __restrict__ c1b,
    const float* __restrict__ c2W, const float* __restrict__ c2b,
    const float* __restrict__ oW, const float* __restrict__ ob,
    float* __restrict__ out) {
  __shared__ float Ps[4][128];
  __shared__ float XAs[4][128];
  __shared__ float XPs[4][32];
  __shared__ float XCs[4][384];
  __shared__ float XC2s[4][256];
  __shared__ float XC3s[4][128];
  const int t = threadIdx.x;
  const int g0 = blockIdx.x * 4;

  // phase A: pool (inline BN of layer 2) + stage XA(relu) / XP
  {
    const int sub = t >> 6, lane = t & 63;
    const int g = g0 + sub;
    const int f0 = lane, f1 = lane + 64;
    float mu0 = psum[f0] * (1.0f / NNODES);
    float va0 = fmaxf(psq[f0] * (1.0f / NNODES) - mu0 * mu0, 0.0f);
    float sc0 = bg[f0] / sqrtf(va0 + 1e-5f);
    float sh0 = bb2[f0] - mu0 * sc0;
    float mu1 = psum[f1] * (1.0f / NNODES);
    float va1 = fmaxf(psq[f1] * (1.0f / NNODES) - mu1 * mu1, 0.0f);
    float sc1 = bg[f1] / sqrtf(va1 + 1e-5f);
    float sh1 = bb2[f1] - mu1 * sc1;
    const int n0 = gp[g], n1 = gp[g + 1];
    float a0 = 0.f, a1 = 0.f;
    for (int n = n0; n < n1; ++n) {
      a0 += relu_f(fmaf(O[(long)n * HIDDEN + f0], sc0, sh0));
      a1 += relu_f(fmaf(O[(long)n * HIDDEN + f1], sc1, sh1));
    }
    Ps[sub][f0] = a0;
    Ps[sub][f1] = a1;
    for (int i = t; i < 512; i += 256) XAs[i >> 7][i & 127] = relu_f(XA[g0 * 128 + i]);
    for (int i = t; i < 128; i += 256) XPs[i >> 5][i & 31] = XP32[g0 * 32 + i];
  }
  __syncthreads();

  // phase B: lig / prot / a2 -> XCs
  {
    const int j = t & 127, pr = t >> 7;
    const int s0 = pr * 2, s1 = pr * 2 + 1;
    float L0 = ligb[j], L1 = L0;
    float A0 = a2b[j], A1 = A0;
    for (int k = 0; k < 128; ++k) {
      const float wl = ligW[k * 128 + j];
      const float wa = a2W[k * 128 + j];
      L0 = fmaf(Ps[s0][k], wl, L0); L1 = fmaf(Ps[s1][k], wl, L1);
      A0 = fmaf(XAs[s0][k], wa, A0); A1 = fmaf(XAs[s1][k], wa, A1);
    }
    float P0 = protb[j], P1 = P0;
    for (int k = 0; k < 32; ++k) {
      const float wp = protW[k * 128 + j];
      P0 = fmaf(XPs[s0][k], wp, P0); P1 = fmaf(XPs[s1][k], wp, P1);
    }
    XCs[s0][j] = relu_f(L0);        XCs[s1][j] = relu_f(L1);
    XCs[s0][128 + j] = relu_f(P0);  XCs[s1][128 + j] = relu_f(P1);
    XCs[s0][256 + j] = relu_f(A0);  XCs[s1][256 + j] = relu_f(A1);
  }
  __syncthreads();

  // phase C: c1 (384 -> 256)
  {
    const int j = t;
    float a[4];
    const float bv = c1b[j];
    for (int s = 0; s < 4; ++s) a[s] = bv;
    for (int k = 0; k < 384; ++k) {
      const float w = c1W[k * 256 + j];
      for (int s = 0; s < 4; ++s) a[s] = fmaf(XCs[s][k], w, a[s]);
    }
    for (int s = 0; s < 4; ++s) XC2s[s][j] = relu_f(a[s]);
  }
  __syncthreads();

  // phase D: c2 (256 -> 128)
  {
    const int j = t & 127, pr = t >> 7;
    const int s0 = pr * 2, s1 = pr * 2 + 1;
    float a0 = c2b[j], a1 = a0;
    for (int k = 0; k < 256; ++k) {
      const float w = c2W[k * 128 + j];
      a0 = fmaf(XC2s[s0][k], w, a0);
      a1 = fmaf(XC2s[s1][k], w, a1);
    }
    XC3s[s0][j] = relu_f(a0);
    XC3s[s1][j] = relu_f(a1);
  }
  __syncthreads();

  // phase E: out (128 -> 1)
  {
    const int w = t >> 6, lane = t & 63;
    float p = XC3s[w][lane] * oW[lane] + XC3s[w][lane + 64] * oW[lane + 64];
    for (int off = 32; off >= 1; off >>= 1) p += __shfl_down(p, off);
    if (lane == 0) out[g0 + w] = p + ob[0];
  }
}

extern "C" void kernel_launch(void* const* d_in, const int* in_sizes, int n_in,
                              void* d_out, int out_size, void* d_ws, size_t ws_size,
                              hipStream_t stream) {
  const float* x_lig = (const float*)d_in[0];
  const float* pseq  = (const float*)d_in[1];
  const float* a2h   = (const float*)d_in[2];
  const int*   ei    = (const int*)d_in[3];
  const int*   batch = (const int*)d_in[4];
  const float* ginW1[3] = {(const float*)d_in[5],  (const float*)d_in[11], (const float*)d_in[17]};
  const float* ginb1[3] = {(const float*)d_in[6],  (const float*)d_in[12], (const float*)d_in[18]};
  const float* ginW2[3] = {(const float*)d_in[7],  (const float*)d_in[13], (const float*)d_in[19]};
  const float* ginb2[3] = {(const float*)d_in[8],  (const float*)d_in[14], (const float*)d_in[20]};
  const float* bng[3]   = {(const float*)d_in[9],  (const float*)d_in[15], (const float*)d_in[21]};
  const float* bnb[3]   = {(const float*)d_in[10], (const float*)d_in[16], (const float*)d_in[22]};
  const float* ligW  = (const float*)d_in[23]; const float* ligb  = (const float*)d_in[24];
  const float* convk = (const float*)d_in[25]; const float* convb = (const float*)d_in[26];
  const float* protW = (const float*)d_in[27]; const float* protb = (const float*)d_in[28];
  const float* a1W   = (const float*)d_in[29]; const float* a1b   = (const float*)d_in[30];
  const float* a2W   = (const float*)d_in[31]; const float* a2b   = (const float*)d_in[32];
  const float* c1W   = (const float*)d_in[33]; const float* c1b   = (const float*)d_in[34];
  const float* c2W   = (const float*)d_in[35]; const float* c2b   = (const float*)d_in[36];
  const float* oW    = (const float*)d_in[37]; const float* ob    = (const float*)d_in[38];

  char* base = (char*)d_ws;
  size_t off = 0;
  auto alloc = [&](size_t bytes) -> char* {
    char* p = base + off;
    off = (off + bytes + 511) & ~size_t(511);
    return p;
  };
  int*   counts  = (int*)alloc(NNODES * 4);
  int*   gcounts = (int*)alloc(NGRAPHS * 4);
  float* bn_sum  = (float*)alloc(3 * 128 * 4);
  float* bn_sq   = (float*)alloc(3 * 128 * 4);
  float* XA      = (float*)alloc(NGRAPHS * 128 * 4);
  const size_t zero_bytes = off;
  short* wsplit   = (short*)alloc(282624 * 2);
  int*   row_ptr  = (int*)alloc((NNODES + 1) * 4);
  int*   nxt      = (int*)alloc(NNODES * 4);
  int*   gptr     = (int*)alloc((NGRAPHS + 1) * 4);
  int*   bsumsA   = (int*)alloc(401 * 4);
  int*   bsumsB   = (int*)alloc(9 * 4);
  int*   csr_sd   = (int*)alloc((size_t)NEDGES * 8);
  float* XP32     = (float*)alloc(NGRAPHS * 32 * 4);
  float* O0       = (float*)alloc((size_t)NNODES * 128 * 4);
  float* O1       = (float*)alloc((size_t)NNODES * 128 * 4);
  (void)ws_size; (void)in_sizes; (void)n_in; (void)out_size;

  hipMemsetAsync(d_ws, 0, zero_bytes, stream);

  prep_kernel<<<NEDGES / 256 + NNODES / 256 + 736, 256, 0, stream>>>(
      ei, batch, counts, gcounts, ginW1[0], ginW2[0], ginW1[1], ginW2[1],
      ginW1[2], ginW2[2], wsplit);
  scan_block2_kernel<<<NNODES / 256 + NGRAPHS / 256, 256, 0, stream>>>(
      counts, row_ptr, bsumsA, gcounts, gptr, bsumsB);
  scan_top2_kernel<<<2, 1024, 0, stream>>>(bsumsA, bsumsB);
  scan_add2_kernel<<<NNODES / 256 + NGRAPHS / 256, 256, 0, stream>>>(
      row_ptr, bsumsA, nxt, gptr, bsumsB);
  scatter_kernel<<<(NEDGES + 255) / 256, 256, 0, stream>>>(ei, nxt, csr_sd);

  fat0_kernel<<<NNODES / 32 + (NGRAPHS / 16) * A2H_NSPLIT + NGRAPHS, 256, 0, stream>>>(
      x_lig, row_ptr, csr_sd, wsplit, ginb1[0], ginb2[0],
      O0, bn_sum, bn_sq, a2h, a1W, a1b, XA, pseq, convk, convb, XP32);

  gin_kernel<<<NNODES / 32, 256, 0, stream>>>(O0, row_ptr, csr_sd,
      wsplit + 86016, ginb1[1], wsplit + 135168, ginb2[1],
      bn_sum, bn_sq, bng[0], bnb[0], O1, bn_sum + 128, bn_sq + 128);
  gin_kernel<<<NNODES / 32, 256, 0, stream>>>(O1, row_ptr, csr_sd,
      wsplit + 184320, ginb1[2], wsplit + 233472, ginb2[2],
      bn_sum + 128, bn_sq + 128, bng[1], bnb[1], O0, bn_sum + 256, bn_sq + 256);

  head_kernel<<<NGRAPHS / 4, 256, 0, stream>>>(O0, gptr,
      bn_sum + 256, bn_sq + 256, bng[2], bnb[2], XP32, XA,
      ligW, ligb, protW, protb, a2W, a2b, c1W, c1b, c2W, c2b, oW, ob, (float*)d_out);
}